// Round 3
// baseline (2629.774 us; speedup 1.0000x reference)
//
#include <hip/hip_runtime.h>

#define TT 512
#define NB 1024
#define SS 64
#define HH 128
#define NA 10

typedef short bf16x8 __attribute__((ext_vector_type(8)));
typedef float f32x4 __attribute__((ext_vector_type(4)));
typedef unsigned short u16;
typedef unsigned int u32;

__device__ __forceinline__ u16 f2bf(float f){
  union { float f; u32 u; } v; v.f = f;
  return (u16)((v.u + 0x7FFFu + ((v.u >> 16) & 1u)) >> 16);
}

__device__ __forceinline__ float sigm(float v){
  return __builtin_amdgcn_rcpf(1.f + __builtin_amdgcn_exp2f(-1.442695040888963f * v));
}
__device__ __forceinline__ float tanh_(float v){
  return 1.f - 2.f * __builtin_amdgcn_rcpf(1.f + __builtin_amdgcn_exp2f(2.885390081777927f * v));
}

// raw barrier: LDS-commit only, leaves global prefetches in flight (no vmcnt drain)
__device__ __forceinline__ void bar_lds(){
  asm volatile("s_waitcnt lgkmcnt(0)" ::: "memory");
  __builtin_amdgcn_s_barrier();
}

// Pack W_hh2 into bf16 MFMA B-fragment order in d_ws. Wave w, ktile kt, gate g,
// lane L reads 16B at w*8192 + (kt*4+g)*512 + L*8; element e is
// col = 128g + 16w + (L&15), k = kt*32 + (L>>4)*8 + e.
__global__ void pack_whh2(const float* __restrict__ Whh2, u16* __restrict__ ws){
  int i = blockIdx.x * 256 + threadIdx.x;   // 65536 total
  int e = i & 7, L = (i >> 3) & 63, fg = i >> 9;
  int g = fg & 3, wk = fg >> 2, kt = wk & 3, w = wk >> 2;
  int col = 128*g + 16*w + (L & 15);
  int k = kt*32 + (L >> 4)*8 + e;
  ws[i] = f2bf(Whh2[col*HH + k]);
}

// 64 blocks x 512 threads (8 waves). Block owns batch rows [16b,16b+16) for all T.
// Wave w owns h-feature slice [16w,16w+16) and its 4 gate tiles (i,f,g,o).
// Granule layout for A-fragments: elem (row,j) -> u16 idx ((j>>3)*16+row)*8+(j&7);
// lane L's A-frag for ktile kt is a linear ds_read_b128 at u16 idx kt*512 + L*8.
//
// 1 barrier per step; h1s/h2s/xs double-buffered. Region(t) computes:
//   part1: acc2(t-1) = b2 + h1(t-1)@Wih2 + h2(t-2)@Whh2(prefetched)  -> h2(t-1)
//          acc1(t)   = b1 + h1(t-1)@Whh1          proj(t-2) on wave 0
//   part2: xs(t+1) <- xreg; issue x(t+2); acc1 += x(t)@Wih1; act1 -> h1(t)
//          issue Whh2 kt01 prefetch for region(t+1)
// All producer->consumer LDS edges cross exactly one bar_lds().
__global__ __launch_bounds__(512, 2)
void lstm_fused(const float* __restrict__ x,
                const float* __restrict__ Whh1f,
                const float* __restrict__ bih1, const float* __restrict__ bhh1,
                const float* __restrict__ Wih1f,
                const float* __restrict__ Wih2f,
                const float* __restrict__ bih2, const float* __restrict__ bhh2,
                const float* __restrict__ Woutf, const float* __restrict__ boutf,
                const u16* __restrict__ wsp,
                float* __restrict__ out)
{
  __shared__ __align__(16) u16 wih1s[32768];
  __shared__ __align__(16) u16 wos[2048];
  __shared__ __align__(16) u16 h1s[2][2048];
  __shared__ __align__(16) u16 h2s[2][2048];
  __shared__ __align__(16) u16 xs[2][1024];

  const int tid = threadIdx.x;
  const int w   = tid >> 6;
  const int L   = tid & 63;
  const int Llo = L & 15;
  const int Lhi = L >> 4;
  const int batch0 = blockIdx.x * 16;

  // ---- one-time: register-resident W_hh1, W_ih2 (bf16 B-fragments) ----
  bf16x8 Whh1r[4][4], Wih2r[4][4];
#pragma unroll
  for (int kt = 0; kt < 4; ++kt)
#pragma unroll
    for (int g = 0; g < 4; ++g){
      int col = 128*g + 16*w + Llo;
      const float* p1 = Whh1f + col*HH + kt*32 + Lhi*8;
      const float* p2 = Wih2f + col*HH + kt*32 + Lhi*8;
      bf16x8 v1, v2;
#pragma unroll
      for (int e = 0; e < 8; ++e){ v1[e] = (short)f2bf(p1[e]); v2[e] = (short)f2bf(p2[e]); }
      Whh1r[kt][g] = v1; Wih2r[kt][g] = v2;
    }

  float bias1[4], bias2[4];
#pragma unroll
  for (int g = 0; g < 4; ++g){
    int col = 128*g + 16*w + Llo;
    bias1[g] = bih1[col] + bhh1[col];
    bias2[g] = bih2[col] + bhh2[col];
  }
  const float boutr = (Llo < NA) ? boutf[Llo] : 0.f;

  // W_out fragments -> LDS (K=128 x N=16, cols >= NA zeroed)
  if (tid < 256){
    int kt = tid >> 6, l = tid & 63, llo = l & 15, lhi = (l >> 4) & 3;
    bf16x8 v;
#pragma unroll
    for (int e = 0; e < 8; ++e) v[e] = 0;
    if (llo < NA){
      const float* p = Woutf + llo*HH + kt*32 + lhi*8;
#pragma unroll
      for (int e = 0; e < 8; ++e) v[e] = (short)f2bf(p[e]);
    }
    *reinterpret_cast<bf16x8*>(&wos[kt*512 + l*8]) = v;
  }

  // W_ih1 fragments -> LDS: u16 idx = w*4096 + (kt*4+g)*512 + L*8 + e
#pragma unroll
  for (int it = 0; it < 64; ++it){
    int i = it*512 + tid;
    int e = i & 7, l = (i >> 3) & 63, fg = i >> 9;
    int g = fg & 3, kt = (fg >> 2) & 1, ww = fg >> 3;
    int col = 128*g + 16*ww + (l & 15);
    int k = kt*32 + (l >> 4)*8 + e;
    wih1s[i] = f2bf(Wih1f[col*SS + k]);
  }

  // zero BOTH buffers of h1s/h2s (h(-1) = h(-2) = 0)
  {
    uint4 z = {0u,0u,0u,0u};
    *reinterpret_cast<uint4*>(&h1s[0][0] + tid*8) = z;
    *reinterpret_cast<uint4*>(&h2s[0][0] + tid*8) = z;
  }

  f32x4 c1 = {0.f,0.f,0.f,0.f}, c2 = {0.f,0.f,0.f,0.f};

  const int afrag = L*8;                                           // + kt*512
  const int hwIdx = (2*w + (Llo >> 3))*128 + Lhi*32 + (Llo & 7);   // + r*8
  const u16* ws_whh2 = wsp + w*8192;
  const int wih1b = w*4096;

  const int xrow = tid >> 5;
  const int xj   = (tid & 31)*2;
  const int xsIdx = ((xj >> 3)*16 + xrow)*8 + (xj & 7);

  // ---- prologue: xs[0] <- x(0); issue x(1); issue Whh2 kt01 prefetch ----
  {
    float2 xv = *reinterpret_cast<const float2*>(x + ((size_t)(batch0 + xrow))*SS + xj);
    u32 p = (u32)f2bf(xv.x) | ((u32)f2bf(xv.y) << 16);
    *reinterpret_cast<u32*>(&xs[0][xsIdx]) = p;
  }
  float2 xreg = *reinterpret_cast<const float2*>(x + ((size_t)NB + batch0 + xrow)*SS + xj);
  bf16x8 wA[8];                      // kt0,kt1 x g0..3
#pragma unroll
  for (int i = 0; i < 8; ++i) wA[i] = *reinterpret_cast<const bf16x8*>(ws_whh2 + i*512 + afrag);

  __syncthreads();

  for (int t = 0; t < TT; ++t){
    const u16* h1r = &h1s[(t+1)&1][0];   // h1(t-1)
    u16*       h1w = &h1s[t&1][0];       // h1(t)
    const u16* h2r = &h2s[t&1][0];       // h2(t-2)
    u16*       h2w = &h2s[(t+1)&1][0];   // h2(t-1)
    const u16* xsr = &xs[t&1][0];        // x(t)
    u16*       xsw = &xs[(t+1)&1][0];    // x(t+1)

    // ================= part 1: layer2(t-1), acc1(t) h-side, proj(t-2) ==========
    bf16x8 wB[8];                      // kt2,kt3 x g0..3 (hidden behind 24 MFMAs)
#pragma unroll
    for (int i = 0; i < 8; ++i) wB[i] = *reinterpret_cast<const bf16x8*>(ws_whh2 + (8+i)*512 + afrag);

    bf16x8 h1f0 = *reinterpret_cast<const bf16x8*>(h1r + afrag);
    bf16x8 h1f1 = *reinterpret_cast<const bf16x8*>(h1r + 512 + afrag);
    bf16x8 h1f2 = *reinterpret_cast<const bf16x8*>(h1r + 2*512 + afrag);
    bf16x8 h1f3 = *reinterpret_cast<const bf16x8*>(h1r + 3*512 + afrag);
    bf16x8 h2f0 = *reinterpret_cast<const bf16x8*>(h2r + afrag);
    bf16x8 h2f1 = *reinterpret_cast<const bf16x8*>(h2r + 512 + afrag);
    bf16x8 h2f2 = *reinterpret_cast<const bf16x8*>(h2r + 2*512 + afrag);
    bf16x8 h2f3 = *reinterpret_cast<const bf16x8*>(h2r + 3*512 + afrag);

    f32x4 acc2[4];
#pragma unroll
    for (int g = 0; g < 4; ++g){
      f32x4 a = (f32x4){bias2[g], bias2[g], bias2[g], bias2[g]};
      a = __builtin_amdgcn_mfma_f32_16x16x32_bf16(h1f0, Wih2r[0][g], a, 0, 0, 0);
      a = __builtin_amdgcn_mfma_f32_16x16x32_bf16(h1f1, Wih2r[1][g], a, 0, 0, 0);
      a = __builtin_amdgcn_mfma_f32_16x16x32_bf16(h1f2, Wih2r[2][g], a, 0, 0, 0);
      a = __builtin_amdgcn_mfma_f32_16x16x32_bf16(h1f3, Wih2r[3][g], a, 0, 0, 0);
      acc2[g] = a;
    }
    // h2(t-2) @ Whh2 : kt0/kt1 from wA (prefetched last region), kt2/kt3 from wB
#pragma unroll
    for (int g = 0; g < 4; ++g){
      acc2[g] = __builtin_amdgcn_mfma_f32_16x16x32_bf16(h2f0, wA[g],   acc2[g], 0, 0, 0);
      acc2[g] = __builtin_amdgcn_mfma_f32_16x16x32_bf16(h2f1, wA[4+g], acc2[g], 0, 0, 0);
    }
#pragma unroll
    for (int g = 0; g < 4; ++g){
      acc2[g] = __builtin_amdgcn_mfma_f32_16x16x32_bf16(h2f2, wB[g],   acc2[g], 0, 0, 0);
      acc2[g] = __builtin_amdgcn_mfma_f32_16x16x32_bf16(h2f3, wB[4+g], acc2[g], 0, 0, 0);
    }

    f32x4 acc1[4];
#pragma unroll
    for (int g = 0; g < 4; ++g){
      f32x4 a = (f32x4){bias1[g], bias1[g], bias1[g], bias1[g]};
      a = __builtin_amdgcn_mfma_f32_16x16x32_bf16(h1f0, Whh1r[0][g], a, 0, 0, 0);
      a = __builtin_amdgcn_mfma_f32_16x16x32_bf16(h1f1, Whh1r[1][g], a, 0, 0, 0);
      a = __builtin_amdgcn_mfma_f32_16x16x32_bf16(h1f2, Whh1r[2][g], a, 0, 0, 0);
      a = __builtin_amdgcn_mfma_f32_16x16x32_bf16(h1f3, Whh1r[3][g], a, 0, 0, 0);
      acc1[g] = a;
    }

    if (t > 0){
      // layer-2 activations -> h2(t-1)
#pragma unroll
      for (int r = 0; r < 4; ++r){
        float iv = sigm(acc2[0][r]);
        float fv = sigm(acc2[1][r]);
        float gv = tanh_(acc2[2][r]);
        float ov = sigm(acc2[3][r]);
        float cn = fv*c2[r] + iv*gv;
        c2[r] = cn;
        h2w[hwIdx + r*8] = f2bf(ov * tanh_(cn));
      }
    }

    if (w == 0 && t >= 2){
      // projection of h2(t-2): reuse h2f* as A-operand
      f32x4 pacc = {boutr, boutr, boutr, boutr};
      pacc = __builtin_amdgcn_mfma_f32_16x16x32_bf16(h2f0, *reinterpret_cast<const bf16x8*>(&wos[afrag]),        pacc, 0, 0, 0);
      pacc = __builtin_amdgcn_mfma_f32_16x16x32_bf16(h2f1, *reinterpret_cast<const bf16x8*>(&wos[512 + afrag]),  pacc, 0, 0, 0);
      pacc = __builtin_amdgcn_mfma_f32_16x16x32_bf16(h2f2, *reinterpret_cast<const bf16x8*>(&wos[1024 + afrag]), pacc, 0, 0, 0);
      pacc = __builtin_amdgcn_mfma_f32_16x16x32_bf16(h2f3, *reinterpret_cast<const bf16x8*>(&wos[1536 + afrag]), pacc, 0, 0, 0);
      if (Llo < NA){
        size_t o = ((size_t)(t-2)*NB + batch0 + Lhi*4)*NA + Llo;
#pragma unroll
        for (int r = 0; r < 4; ++r) out[o + (size_t)r*NA] = pacc[r];
      }
    }

    // ================= part 2: stage x, layer1(t) x-side + act =================
    {
      u32 p = (u32)f2bf(xreg.x) | ((u32)f2bf(xreg.y) << 16);
      *reinterpret_cast<u32*>(xsw + xsIdx) = p;
    }
    if (t + 2 < TT)
      xreg = *reinterpret_cast<const float2*>(x + ((size_t)(t+2)*NB + batch0 + xrow)*SS + xj);

    {
      bf16x8 xf0 = *reinterpret_cast<const bf16x8*>(xsr + afrag);
      bf16x8 xf1 = *reinterpret_cast<const bf16x8*>(xsr + 512 + afrag);
#pragma unroll
      for (int g = 0; g < 4; ++g){
        bf16x8 w0f = *reinterpret_cast<const bf16x8*>(&wih1s[wih1b + g*512 + afrag]);
        bf16x8 w1f = *reinterpret_cast<const bf16x8*>(&wih1s[wih1b + (4+g)*512 + afrag]);
        acc1[g] = __builtin_amdgcn_mfma_f32_16x16x32_bf16(xf0, w0f, acc1[g], 0, 0, 0);
        acc1[g] = __builtin_amdgcn_mfma_f32_16x16x32_bf16(xf1, w1f, acc1[g], 0, 0, 0);
      }
    }

    // layer-1 activations -> h1(t)
#pragma unroll
    for (int r = 0; r < 4; ++r){
      float iv = sigm(acc1[0][r]);
      float fv = sigm(acc1[1][r]);
      float gv = tanh_(acc1[2][r]);
      float ov = sigm(acc1[3][r]);
      float cn = fv*c1[r] + iv*gv;
      c1[r] = cn;
      h1w[hwIdx + r*8] = f2bf(ov * tanh_(cn));
    }

    // prefetch Whh2 kt0/kt1 for region(t+1) — stays in flight across the barrier
#pragma unroll
    for (int i = 0; i < 8; ++i) wA[i] = *reinterpret_cast<const bf16x8*>(ws_whh2 + i*512 + afrag);

    bar_lds();
  }

  // ================= epilogue: h2(511), proj(510), proj(511) =================
  {
    const u16* h1r = &h1s[(TT+1)&1][0];   // h1(511)
    const u16* h2r = &h2s[TT&1][0];       // h2(510)
    u16*       h2w = &h2s[(TT+1)&1][0];

    bf16x8 wB[8];
#pragma unroll
    for (int i = 0; i < 8; ++i) wB[i] = *reinterpret_cast<const bf16x8*>(ws_whh2 + (8+i)*512 + afrag);

    bf16x8 h1f0 = *reinterpret_cast<const bf16x8*>(h1r + afrag);
    bf16x8 h1f1 = *reinterpret_cast<const bf16x8*>(h1r + 512 + afrag);
    bf16x8 h1f2 = *reinterpret_cast<const bf16x8*>(h1r + 2*512 + afrag);
    bf16x8 h1f3 = *reinterpret_cast<const bf16x8*>(h1r + 3*512 + afrag);
    bf16x8 h2f0 = *reinterpret_cast<const bf16x8*>(h2r + afrag);
    bf16x8 h2f1 = *reinterpret_cast<const bf16x8*>(h2r + 512 + afrag);
    bf16x8 h2f2 = *reinterpret_cast<const bf16x8*>(h2r + 2*512 + afrag);
    bf16x8 h2f3 = *reinterpret_cast<const bf16x8*>(h2r + 3*512 + afrag);

    f32x4 acc2[4];
#pragma unroll
    for (int g = 0; g < 4; ++g){
      f32x4 a = (f32x4){bias2[g], bias2[g], bias2[g], bias2[g]};
      a = __builtin_amdgcn_mfma_f32_16x16x32_bf16(h1f0, Wih2r[0][g], a, 0, 0, 0);
      a = __builtin_amdgcn_mfma_f32_16x16x32_bf16(h1f1, Wih2r[1][g], a, 0, 0, 0);
      a = __builtin_amdgcn_mfma_f32_16x16x32_bf16(h1f2, Wih2r[2][g], a, 0, 0, 0);
      a = __builtin_amdgcn_mfma_f32_16x16x32_bf16(h1f3, Wih2r[3][g], a, 0, 0, 0);
      a = __builtin_amdgcn_mfma_f32_16x16x32_bf16(h2f0, wA[g],   a, 0, 0, 0);
      a = __builtin_amdgcn_mfma_f32_16x16x32_bf16(h2f1, wA[4+g], a, 0, 0, 0);
      a = __builtin_amdgcn_mfma_f32_16x16x32_bf16(h2f2, wB[g],   a, 0, 0, 0);
      a = __builtin_amdgcn_mfma_f32_16x16x32_bf16(h2f3, wB[4+g], a, 0, 0, 0);
      acc2[g] = a;
    }
#pragma unroll
    for (int r = 0; r < 4; ++r){
      float iv = sigm(acc2[0][r]);
      float fv = sigm(acc2[1][r]);
      float gv = tanh_(acc2[2][r]);
      float ov = sigm(acc2[3][r]);
      float cn = fv*c2[r] + iv*gv;
      c2[r] = cn;
      h2w[hwIdx + r*8] = f2bf(ov * tanh_(cn));
    }

    if (w == 0){   // proj(510) from h2f*
      f32x4 pacc = {boutr, boutr, boutr, boutr};
      pacc = __builtin_amdgcn_mfma_f32_16x16x32_bf16(h2f0, *reinterpret_cast<const bf16x8*>(&wos[afrag]),        pacc, 0, 0, 0);
      pacc = __builtin_amdgcn_mfma_f32_16x16x32_bf16(h2f1, *reinterpret_cast<const bf16x8*>(&wos[512 + afrag]),  pacc, 0, 0, 0);
      pacc = __builtin_amdgcn_mfma_f32_16x16x32_bf16(h2f2, *reinterpret_cast<const bf16x8*>(&wos[1024 + afrag]), pacc, 0, 0, 0);
      pacc = __builtin_amdgcn_mfma_f32_16x16x32_bf16(h2f3, *reinterpret_cast<const bf16x8*>(&wos[1536 + afrag]), pacc, 0, 0, 0);
      if (Llo < NA){
        size_t o = ((size_t)(TT-2)*NB + batch0 + Lhi*4)*NA + Llo;
#pragma unroll
        for (int r = 0; r < 4; ++r) out[o + (size_t)r*NA] = pacc[r];
      }
    }

    bar_lds();

    if (w == 0){   // proj(511) from h2s[1]
      const u16* h2f = &h2s[(TT+1)&1][0];
      bf16x8 a0 = *reinterpret_cast<const bf16x8*>(h2f + afrag);
      bf16x8 a1 = *reinterpret_cast<const bf16x8*>(h2f + 512 + afrag);
      bf16x8 a2 = *reinterpret_cast<const bf16x8*>(h2f + 2*512 + afrag);
      bf16x8 a3 = *reinterpret_cast<const bf16x8*>(h2f + 3*512 + afrag);
      f32x4 pacc = {boutr, boutr, boutr, boutr};
      pacc = __builtin_amdgcn_mfma_f32_16x16x32_bf16(a0, *reinterpret_cast<const bf16x8*>(&wos[afrag]),        pacc, 0, 0, 0);
      pacc = __builtin_amdgcn_mfma_f32_16x16x32_bf16(a1, *reinterpret_cast<const bf16x8*>(&wos[512 + afrag]),  pacc, 0, 0, 0);
      pacc = __builtin_amdgcn_mfma_f32_16x16x32_bf16(a2, *reinterpret_cast<const bf16x8*>(&wos[1024 + afrag]), pacc, 0, 0, 0);
      pacc = __builtin_amdgcn_mfma_f32_16x16x32_bf16(a3, *reinterpret_cast<const bf16x8*>(&wos[1536 + afrag]), pacc, 0, 0, 0);
      if (Llo < NA){
        size_t o = ((size_t)(TT-1)*NB + batch0 + Lhi*4)*NA + Llo;
#pragma unroll
        for (int r = 0; r < 4; ++r) out[o + (size_t)r*NA] = pacc[r];
      }
    }
  }
}

extern "C" void kernel_launch(void* const* d_in, const int* in_sizes, int n_in,
                              void* d_out, int out_size, void* d_ws, size_t ws_size,
                              hipStream_t stream){
  (void)in_sizes; (void)n_in; (void)out_size; (void)ws_size;
  const float* xp   = (const float*)d_in[0];
  const float* wih1 = (const float*)d_in[1];
  const float* whh1 = (const float*)d_in[2];
  const float* bih1 = (const float*)d_in[3];
  const float* bhh1 = (const float*)d_in[4];
  const float* wih2 = (const float*)d_in[5];
  const float* whh2 = (const float*)d_in[6];
  const float* bih2 = (const float*)d_in[7];
  const float* bhh2 = (const float*)d_in[8];
  const float* wout = (const float*)d_in[9];
  const float* bout = (const float*)d_in[10];
  u16*   wsp  = (u16*)d_ws;
  float* outp = (float*)d_out;

  hipLaunchKernelGGL(pack_whh2, dim3(256), dim3(256), 0, stream, whh2, wsp);
  hipLaunchKernelGGL(lstm_fused, dim3(64), dim3(512), 0, stream,
                     xp, whh1, bih1, bhh1, wih1, wih2, bih2, bhh2, wout, bout, wsp, outp);
}